// Round 6
// baseline (63.011 us; speedup 1.0000x reference)
//
#include <hip/hip_runtime.h>
#include <cmath>

namespace {
constexpr int G8   = 8;
constexpr int O8   = 8;
constexpr int I8   = 8;
constexpr int KS   = 7;
constexpr int S49  = KS * KS;        // 49
constexpr int CIN  = 128;
constexpr int COUT = 128;
constexpr int SLICE = G8 * S49;      // 392 floats per (co,ci)
constexpr int CI_PER_BLK = 2;
constexpr int NT = 448;              // 7 waves; threads 0..391 map to (i,s)
}

__global__ __launch_bounds__(NT) void expand_kernel(
    const float* __restrict__ weight,   // [COUT, CIN, G, 7, 7]
    const float* __restrict__ in_H,     // [8]
    const float* __restrict__ out_H,    // [8]
    const float* __restrict__ grid_Rn,  // [7,7,2]
    const float* __restrict__ mask,     // [7,7]
    float* __restrict__ out)            // [COUT, O, CIN, I, 7, 7]
{
    __shared__ float Wl[CI_PER_BLK][SLICE];
    __shared__ float gxy[2 * S49];
    __shared__ float msk[S49];
    __shared__ float trig[2 * O8];
    __shared__ unsigned int hg[O8 * I8];
    __shared__ float hw[O8 * I8];

    const int tid = threadIdx.x;
    const int bx  = blockIdx.x;
    const int co  = bx >> 6;                 // 64 blocks per co (128 ci / 2)
    const int ci0 = (bx & 63) * CI_PER_BLK;

    // ---- staging (disjoint thread ranges, one pass) ----
    if (tid < (CI_PER_BLK * SLICE) / 4) {    // 196 float4 = 2*392 floats
        const float4* src = reinterpret_cast<const float4*>(
            weight + (size_t)(co * CIN + ci0) * SLICE);
        reinterpret_cast<float4*>(&Wl[0][0])[tid] = src[tid];
    } else if (tid >= 196 && tid < 196 + 2 * S49) {
        gxy[tid - 196] = grid_Rn[tid - 196];
    } else if (tid >= 294 && tid < 294 + S49) {
        msk[tid - 294] = mask[tid - 294];
    } else if (tid >= 344 && tid < 344 + O8) {
        const int o = tid - 344;
        const float a = -out_H[o];           // out_inv, same as reference
        trig[2 * o]     = cosf(a);
        trig[2 * o + 1] = sinf(a);
    } else if (tid >= 384 && tid < 384 + O8 * I8) {
        const int t = tid - 384;
        const int o = t >> 3, i = t & 7;
        const float TP   = 6.28318530717958647692f;   // float32(2*pi)
        const float STEP = 0.78539816339744830961f;   // float32(2*pi/8)
        float q = -out_H[o] + in_H[i];
        float m = fmodf(q, TP);
        if (m < 0.0f) m += TP;               // jnp.mod semantics
        const float pos = m / STEP;
        const float b = floorf(pos);
        const int i0 = ((int)b) & 7;         // b in [0,8], 8&7==0 matches %8
        const int i1 = (i0 + 1) & 7;
        hg[t] = (unsigned)(i0 * S49) | ((unsigned)(i1 * S49) << 16);
        hw[t] = pos - b;
    }
    __syncthreads();

    if (tid >= SLICE) return;
    const int e = tid;                       // e = i*49 + s
    const int i = e / S49;
    const int s = e - i * S49;
    const float gx = gxy[2 * s];
    const float gy = gxy[2 * s + 1];
    const float mv = msk[s];

    size_t obase = ((size_t)(co * O8) * CIN + ci0) * SLICE + e;

    #pragma unroll
    for (int o = 0; o < O8; ++o) {
        const float c  = trig[2 * o];
        const float sn = trig[2 * o + 1];
        const float rx = c * gx - sn * gy;   // left_apply_to_Rn
        const float ry = sn * gx + c * gy;
        const float px = (rx + 1.0f) * 0.5f * (float)(KS - 1);
        const float py = (ry + 1.0f) * 0.5f * (float)(KS - 1);
        const float fx0 = floorf(px), fy0 = floorf(py);
        const float wx = px - fx0, wy = py - fy0;
        const int x0 = (int)fx0, y0 = (int)fy0;
        const int x1 = x0 + 1,   y1 = y0 + 1;
        const int xc0 = min(max(x0, 0), KS - 1);
        const int xc1 = min(max(x1, 0), KS - 1);
        const int yc0 = min(max(y0, 0), KS - 1);
        const int yc1 = min(max(y1, 0), KS - 1);
        const bool ix0 = (x0 >= 0) && (x0 <= KS - 1);
        const bool ix1 = (x1 >= 0) && (x1 <= KS - 1);
        const bool iy0 = (y0 >= 0) && (y0 <= KS - 1);
        const bool iy1 = (y1 >= 0) && (y1 <= KS - 1);
        float w00 = (1.0f - wx) * (1.0f - wy); w00 = (ix0 && iy0) ? w00 : 0.0f;
        float w10 = wx * (1.0f - wy);          w10 = (ix1 && iy0) ? w10 : 0.0f;
        float w01 = (1.0f - wx) * wy;          w01 = (ix0 && iy1) ? w01 : 0.0f;
        float w11 = wx * wy;                   w11 = (ix1 && iy1) ? w11 : 0.0f;

        const unsigned hp = hg[(o << 3) + i];
        const float    wh = hw[(o << 3) + i];
        const int g0 = (int)(hp & 0xffffu);
        const int g1 = (int)(hp >> 16);
        const int r0 = yc0 * KS, r1 = yc1 * KS;
        const int p00 = g0 + r0 + xc0, p10 = g0 + r0 + xc1;
        const int p01 = g0 + r1 + xc0, p11 = g0 + r1 + xc1;
        const int q00 = g1 + r0 + xc0, q10 = g1 + r0 + xc1;
        const int q01 = g1 + r1 + xc0, q11 = g1 + r1 + xc1;

        #pragma unroll
        for (int cc = 0; cc < CI_PER_BLK; ++cc) {
            const float* W = Wl[cc];
            const float a0 = w00 * W[p00] + w10 * W[p10] + w01 * W[p01] + w11 * W[p11];
            const float a1 = w00 * W[q00] + w10 * W[q10] + w01 * W[q01] + w11 * W[q11];
            out[obase + (size_t)cc * SLICE] = ((1.0f - wh) * a0 + wh * a1) * mv;
        }
        obase += (size_t)CIN * SLICE;        // advance o by 128*392
    }
}

extern "C" void kernel_launch(void* const* d_in, const int* in_sizes, int n_in,
                              void* d_out, int out_size, void* d_ws, size_t ws_size,
                              hipStream_t stream) {
    const float* weight  = (const float*)d_in[0];
    const float* in_H    = (const float*)d_in[1];
    const float* out_H   = (const float*)d_in[2];
    /* d_in[3] = grid_H (unused) */
    const float* grid_Rn = (const float*)d_in[4];
    const float* mask    = (const float*)d_in[5];
    float* outp = (float*)d_out;

    const int nblocks = COUT * (CIN / CI_PER_BLK);  // 8192
    hipLaunchKernelGGL(expand_kernel, dim3(nblocks), dim3(NT), 0, stream,
                       weight, in_H, out_H, grid_Rn, mask, outp);
}

// Round 8
// 42.271 us; speedup vs baseline: 1.4906x; 1.4906x over previous
//
#include <hip/hip_runtime.h>
#include <cmath>

namespace {
constexpr int G8   = 8;
constexpr int O8   = 8;
constexpr int I8   = 8;
constexpr int KS   = 7;
constexpr int S49  = KS * KS;        // 49
constexpr int CIN  = 128;
constexpr int COUT = 128;
constexpr int SLICE = G8 * S49;      // 392 floats per (co,ci)
constexpr int CI_PER_BLK = 4;        // ci packed into float4 LDS lanes
constexpr int NT = 448;              // threads 0..391 map to (i,s)
}

__global__ __launch_bounds__(NT) void expand_kernel(
    const float* __restrict__ weight,   // [COUT, CIN, G, 7, 7]
    const float* __restrict__ in_H,     // [8]
    const float* __restrict__ out_H,    // [8]
    const float* __restrict__ grid_Rn,  // [7,7,2]
    const float* __restrict__ mask,     // [7,7]
    float* __restrict__ out)            // [COUT, O, CIN, I, 7, 7]
{
    __shared__ float4 Wl[SLICE];        // [g*49+p] -> {ci0,ci0+1,ci0+2,ci0+3}
    __shared__ float gxy[2 * S49];
    __shared__ float msk[S49];
    __shared__ float trig[2 * O8];
    __shared__ unsigned int hg[O8 * I8];
    __shared__ float hw[O8 * I8];

    const int tid = threadIdx.x;
    const int bx  = blockIdx.x;
    const int co  = bx >> 5;                 // 32 blocks per co (128 ci / 4)
    const int ci0 = (bx & 31) * CI_PER_BLK;

    // ---- weight staging: transpose 4 ci-slices into float4-interleaved LDS ----
    if (tid < SLICE) {
        const float* b0 = weight + (size_t)(co * CIN + ci0) * SLICE + tid;
        float4 v;
        v.x = b0[0];
        v.y = b0[SLICE];
        v.z = b0[2 * SLICE];
        v.w = b0[3 * SLICE];
        Wl[tid] = v;
    }
    // ---- small tables (threads 0..218, overlapping with weight staging) ----
    if (tid < 2 * S49) {
        gxy[tid] = grid_Rn[tid];
    } else if (tid < 3 * S49) {
        msk[tid - 2 * S49] = mask[tid - 2 * S49];
    } else if (tid < 3 * S49 + O8) {         // 147..154
        const int o = tid - 3 * S49;
        const float a = -out_H[o];           // out_inv, same as reference
        trig[2 * o]     = cosf(a);
        trig[2 * o + 1] = sinf(a);
    } else if (tid < 3 * S49 + O8 + O8 * I8) {  // 155..218
        const int t = tid - (3 * S49 + O8);
        const int o = t >> 3, i = t & 7;
        const float TP   = 6.28318530717958647692f;   // float32(2*pi)
        const float STEP = 0.78539816339744830961f;   // float32(2*pi/8)
        float q = -out_H[o] + in_H[i];
        float m = fmodf(q, TP);
        if (m < 0.0f) m += TP;               // jnp.mod semantics
        const float pos = m / STEP;
        const float b = floorf(pos);
        const int i0 = ((int)b) & 7;         // b in [0,8], 8&7==0 matches %8
        const int i1 = (i0 + 1) & 7;
        hg[t] = (unsigned)(i0 * S49) | ((unsigned)(i1 * S49) << 16);
        hw[t] = pos - b;
    }
    __syncthreads();

    if (tid >= SLICE) return;
    const int i = tid / S49;                 // 0..7
    const int s = tid - i * S49;             // 0..48
    const float gx = gxy[2 * s];
    const float gy = gxy[2 * s + 1];
    const float mv = msk[s];

    size_t obase = ((size_t)(co * O8) * CIN + ci0) * SLICE + tid;

    #pragma unroll
    for (int o = 0; o < O8; ++o) {
        const float c  = trig[2 * o];
        const float sn = trig[2 * o + 1];
        const float rx = c * gx - sn * gy;   // left_apply_to_Rn
        const float ry = sn * gx + c * gy;
        const float px = (rx + 1.0f) * 0.5f * (float)(KS - 1);
        const float py = (ry + 1.0f) * 0.5f * (float)(KS - 1);
        const float fx0 = floorf(px), fy0 = floorf(py);
        const float wx = px - fx0, wy = py - fy0;
        const int x0 = (int)fx0, y0 = (int)fy0;
        const int x1 = x0 + 1,   y1 = y0 + 1;
        const int xc0 = min(max(x0, 0), KS - 1);
        const int xc1 = min(max(x1, 0), KS - 1);
        const int yc0 = min(max(y0, 0), KS - 1);
        const int yc1 = min(max(y1, 0), KS - 1);
        const bool ix0 = (x0 >= 0) && (x0 <= KS - 1);
        const bool ix1 = (x1 >= 0) && (x1 <= KS - 1);
        const bool iy0 = (y0 >= 0) && (y0 <= KS - 1);
        const bool iy1 = (y1 >= 0) && (y1 <= KS - 1);
        float w00 = (1.0f - wx) * (1.0f - wy); w00 = (ix0 && iy0) ? w00 : 0.0f;
        float w10 = wx * (1.0f - wy);          w10 = (ix1 && iy0) ? w10 : 0.0f;
        float w01 = (1.0f - wx) * wy;          w01 = (ix0 && iy1) ? w01 : 0.0f;
        float w11 = wx * wy;                   w11 = (ix1 && iy1) ? w11 : 0.0f;

        const unsigned hp = hg[(o << 3) + i];
        const float    wh = hw[(o << 3) + i];
        const int g0 = (int)(hp & 0xffffu);
        const int g1 = (int)(hp >> 16);
        const int t00 = yc0 * KS + xc0, t10 = yc0 * KS + xc1;
        const int t01 = yc1 * KS + xc0, t11 = yc1 * KS + xc1;

        float ax, ay, az, aw;
        const bool lo = (wh <= 1e-4f);
        const bool hi = (wh >= 1.0f - 1e-4f);
        if (lo || hi) {
            // degenerate H-blend: single slice; dropped term <= 1e-4*|W| ~ 5e-7
            const int   g  = lo ? g0 : g1;
            const float sc = (lo ? (1.0f - wh) : wh) * mv;
            const float4 v00 = Wl[g + t00];
            const float4 v10 = Wl[g + t10];
            const float4 v01 = Wl[g + t01];
            const float4 v11 = Wl[g + t11];
            ax = sc * (w00 * v00.x + w10 * v10.x + w01 * v01.x + w11 * v11.x);
            ay = sc * (w00 * v00.y + w10 * v10.y + w01 * v01.y + w11 * v11.y);
            az = sc * (w00 * v00.z + w10 * v10.z + w01 * v01.z + w11 * v11.z);
            aw = sc * (w00 * v00.w + w10 * v10.w + w01 * v01.w + w11 * v11.w);
        } else {
            const float4 u00 = Wl[g0 + t00];
            const float4 u10 = Wl[g0 + t10];
            const float4 u01 = Wl[g0 + t01];
            const float4 u11 = Wl[g0 + t11];
            const float4 v00 = Wl[g1 + t00];
            const float4 v10 = Wl[g1 + t10];
            const float4 v01 = Wl[g1 + t01];
            const float4 v11 = Wl[g1 + t11];
            const float wA = (1.0f - wh), wB = wh;
            ax = mv * (wA * (w00 * u00.x + w10 * u10.x + w01 * u01.x + w11 * u11.x)
                     + wB * (w00 * v00.x + w10 * v10.x + w01 * v01.x + w11 * v11.x));
            ay = mv * (wA * (w00 * u00.y + w10 * u10.y + w01 * u01.y + w11 * u11.y)
                     + wB * (w00 * v00.y + w10 * v10.y + w01 * v01.y + w11 * v11.y));
            az = mv * (wA * (w00 * u00.z + w10 * u10.z + w01 * u01.z + w11 * u11.z)
                     + wB * (w00 * v00.z + w10 * v10.z + w01 * v01.z + w11 * v11.z));
            aw = mv * (wA * (w00 * u00.w + w10 * u10.w + w01 * u01.w + w11 * u11.w)
                     + wB * (w00 * v00.w + w10 * v10.w + w01 * v01.w + w11 * v11.w));
        }

        out[obase]             = ax;
        out[obase + SLICE]     = ay;
        out[obase + 2 * SLICE] = az;
        out[obase + 3 * SLICE] = aw;
        obase += (size_t)CIN * SLICE;        // advance o by 128*392
    }
}

extern "C" void kernel_launch(void* const* d_in, const int* in_sizes, int n_in,
                              void* d_out, int out_size, void* d_ws, size_t ws_size,
                              hipStream_t stream) {
    const float* weight  = (const float*)d_in[0];
    const float* in_H    = (const float*)d_in[1];
    const float* out_H   = (const float*)d_in[2];
    /* d_in[3] = grid_H (unused) */
    const float* grid_Rn = (const float*)d_in[4];
    const float* mask    = (const float*)d_in[5];
    float* outp = (float*)d_out;

    const int nblocks = COUT * (CIN / CI_PER_BLK);  // 4096
    hipLaunchKernelGGL(expand_kernel, dim3(nblocks), dim3(NT), 0, stream,
                       weight, in_H, out_H, grid_Rn, mask, outp);
}

// Round 9
// 41.020 us; speedup vs baseline: 1.5361x; 1.0305x over previous
//
#include <hip/hip_runtime.h>
#include <cmath>

namespace {
constexpr int G8   = 8;
constexpr int O8   = 8;
constexpr int I8   = 8;
constexpr int KS   = 7;
constexpr int S49  = KS * KS;        // 49
constexpr int CIN  = 128;
constexpr int COUT = 128;
constexpr int SLICE = G8 * S49;      // 392 floats per (co,ci)
constexpr int CI_PER_BLK = 4;        // ci packed into float4 LDS lanes
constexpr int NT = 448;              // threads 0..391 map to (i,s)
}

__global__ __launch_bounds__(NT) void expand_kernel(
    const float* __restrict__ weight,   // [COUT, CIN, G, 7, 7]
    const float* __restrict__ in_H,     // [8]
    const float* __restrict__ out_H,    // [8]
    const float* __restrict__ grid_Rn,  // [7,7,2]
    const float* __restrict__ mask,     // [7,7]
    float* __restrict__ out)            // [COUT, O, CIN, I, 7, 7]
{
    __shared__ float4 Wl[SLICE];        // [g*49+p] -> {ci0..ci0+3}  (6272 B)
    __shared__ float4 wtab[O8 * S49];   // per-(o,s) bilinear weights * mask
    __shared__ unsigned int ttab[O8 * S49]; // per-(o,s) packed tap indices
    __shared__ unsigned int hg[O8 * I8];
    __shared__ float hw[O8 * I8];

    const int tid = threadIdx.x;
    const int bx  = blockIdx.x;
    const int co  = bx >> 5;                 // 32 blocks per co (128 ci / 4)
    const int ci0 = (bx & 31) * CI_PER_BLK;

    // ---- weight staging: transpose 4 ci-slices into float4-interleaved LDS ----
    if (tid < SLICE) {
        const float* b0 = weight + (size_t)(co * CIN + ci0) * SLICE + tid;
        float4 v;
        v.x = b0[0];
        v.y = b0[SLICE];
        v.z = b0[2 * SLICE];
        v.w = b0[3 * SLICE];
        Wl[tid] = v;

        // ---- geometry tables: one thread per (o,s) combo ----
        const int o = tid / S49;
        const int s = tid - o * S49;
        const float gx = grid_Rn[2 * s];
        const float gy = grid_Rn[2 * s + 1];
        const float mv = mask[s];
        const float a  = -out_H[o];          // out_inv, same as reference
        const float c  = cosf(a);
        const float sn = sinf(a);
        const float rx = c * gx - sn * gy;   // left_apply_to_Rn
        const float ry = sn * gx + c * gy;
        const float px = (rx + 1.0f) * 0.5f * (float)(KS - 1);
        const float py = (ry + 1.0f) * 0.5f * (float)(KS - 1);
        const float fx0 = floorf(px), fy0 = floorf(py);
        const float wx = px - fx0, wy = py - fy0;
        const int x0 = (int)fx0, y0 = (int)fy0;
        const int x1 = x0 + 1,   y1 = y0 + 1;
        const int xc0 = min(max(x0, 0), KS - 1);
        const int xc1 = min(max(x1, 0), KS - 1);
        const int yc0 = min(max(y0, 0), KS - 1);
        const int yc1 = min(max(y1, 0), KS - 1);
        const bool ix0 = (x0 >= 0) && (x0 <= KS - 1);
        const bool ix1 = (x1 >= 0) && (x1 <= KS - 1);
        const bool iy0 = (y0 >= 0) && (y0 <= KS - 1);
        const bool iy1 = (y1 >= 0) && (y1 <= KS - 1);
        float w00 = (1.0f - wx) * (1.0f - wy); w00 = (ix0 && iy0) ? w00 : 0.0f;
        float w10 = wx * (1.0f - wy);          w10 = (ix1 && iy0) ? w10 : 0.0f;
        float w01 = (1.0f - wx) * wy;          w01 = (ix0 && iy1) ? w01 : 0.0f;
        float w11 = wx * wy;                   w11 = (ix1 && iy1) ? w11 : 0.0f;
        float4 wv;                            // premultiplied by mask (bf16-absorbed reassoc)
        wv.x = w00 * mv; wv.y = w10 * mv; wv.z = w01 * mv; wv.w = w11 * mv;
        wtab[tid] = wv;
        const unsigned t00 = (unsigned)(yc0 * KS + xc0);
        const unsigned t10 = (unsigned)(yc0 * KS + xc1);
        const unsigned t01 = (unsigned)(yc1 * KS + xc0);
        const unsigned t11 = (unsigned)(yc1 * KS + xc1);
        ttab[tid] = t00 | (t10 << 8) | (t01 << 16) | (t11 << 24);
    }
    if (tid < O8 * I8) {                     // threads 0..63: H-interp table
        const int o = tid >> 3, i = tid & 7;
        const float TP   = 6.28318530717958647692f;   // float32(2*pi)
        const float STEP = 0.78539816339744830961f;   // float32(2*pi/8)
        float q = -out_H[o] + in_H[i];
        float m = fmodf(q, TP);
        if (m < 0.0f) m += TP;               // jnp.mod semantics
        const float pos = m / STEP;
        const float b = floorf(pos);
        const int i0 = ((int)b) & 7;         // b in [0,8], 8&7==0 matches %8
        const int i1 = (i0 + 1) & 7;
        hg[tid] = (unsigned)(i0 * S49) | ((unsigned)(i1 * S49) << 16);
        hw[tid] = pos - b;
    }
    __syncthreads();

    if (tid >= SLICE) return;
    const int i = tid / S49;                 // 0..7
    const int s = tid - i * S49;             // 0..48

    size_t obase = ((size_t)(co * O8) * CIN + ci0) * SLICE + tid;

    #pragma unroll
    for (int o = 0; o < O8; ++o) {
        const float4 wv = wtab[o * S49 + s];
        const unsigned tp = ttab[o * S49 + s];
        const int t00 = (int)(tp & 0xffu);
        const int t10 = (int)((tp >> 8) & 0xffu);
        const int t01 = (int)((tp >> 16) & 0xffu);
        const int t11 = (int)(tp >> 24);

        const unsigned hp = hg[(o << 3) + i];
        const float    wh = hw[(o << 3) + i];
        const int g0 = (int)(hp & 0xffffu);
        const int g1 = (int)(hp >> 16);

        float ax, ay, az, aw;
        const bool lo = (wh <= 1e-4f);
        const bool hi = (wh >= 1.0f - 1e-4f);
        if (lo || hi) {
            // degenerate H-blend: single slice; dropped term <= 1e-4*|W| ~ 5e-7
            const int   g  = lo ? g0 : g1;
            const float sc = lo ? (1.0f - wh) : wh;
            const float4 v00 = Wl[g + t00];
            const float4 v10 = Wl[g + t10];
            const float4 v01 = Wl[g + t01];
            const float4 v11 = Wl[g + t11];
            ax = sc * (wv.x * v00.x + wv.y * v10.x + wv.z * v01.x + wv.w * v11.x);
            ay = sc * (wv.x * v00.y + wv.y * v10.y + wv.z * v01.y + wv.w * v11.y);
            az = sc * (wv.x * v00.z + wv.y * v10.z + wv.z * v01.z + wv.w * v11.z);
            aw = sc * (wv.x * v00.w + wv.y * v10.w + wv.z * v01.w + wv.w * v11.w);
        } else {
            const float4 u00 = Wl[g0 + t00];
            const float4 u10 = Wl[g0 + t10];
            const float4 u01 = Wl[g0 + t01];
            const float4 u11 = Wl[g0 + t11];
            const float4 v00 = Wl[g1 + t00];
            const float4 v10 = Wl[g1 + t10];
            const float4 v01 = Wl[g1 + t01];
            const float4 v11 = Wl[g1 + t11];
            const float wA = (1.0f - wh), wB = wh;
            ax = wA * (wv.x * u00.x + wv.y * u10.x + wv.z * u01.x + wv.w * u11.x)
               + wB * (wv.x * v00.x + wv.y * v10.x + wv.z * v01.x + wv.w * v11.x);
            ay = wA * (wv.x * u00.y + wv.y * u10.y + wv.z * u01.y + wv.w * u11.y)
               + wB * (wv.x * v00.y + wv.y * v10.y + wv.z * v01.y + wv.w * v11.y);
            az = wA * (wv.x * u00.z + wv.y * u10.z + wv.z * u01.z + wv.w * u11.z)
               + wB * (wv.x * v00.z + wv.y * v10.z + wv.z * v01.z + wv.w * v11.z);
            aw = wA * (wv.x * u00.w + wv.y * u10.w + wv.z * u01.w + wv.w * u11.w)
               + wB * (wv.x * v00.w + wv.y * v10.w + wv.z * v01.w + wv.w * v11.w);
        }

        out[obase]             = ax;
        out[obase + SLICE]     = ay;
        out[obase + 2 * SLICE] = az;
        out[obase + 3 * SLICE] = aw;
        obase += (size_t)CIN * SLICE;        // advance o by 128*392
    }
}

extern "C" void kernel_launch(void* const* d_in, const int* in_sizes, int n_in,
                              void* d_out, int out_size, void* d_ws, size_t ws_size,
                              hipStream_t stream) {
    const float* weight  = (const float*)d_in[0];
    const float* in_H    = (const float*)d_in[1];
    const float* out_H   = (const float*)d_in[2];
    /* d_in[3] = grid_H (unused) */
    const float* grid_Rn = (const float*)d_in[4];
    const float* mask    = (const float*)d_in[5];
    float* outp = (float*)d_out;

    const int nblocks = COUT * (CIN / CI_PER_BLK);  // 4096
    hipLaunchKernelGGL(expand_kernel, dim3(nblocks), dim3(NT), 0, stream,
                       weight, in_H, out_H, grid_Rn, mask, outp);
}

// Round 10
// 40.588 us; speedup vs baseline: 1.5525x; 1.0107x over previous
//
#include <hip/hip_runtime.h>
#include <cmath>

namespace {
constexpr int G8   = 8;
constexpr int O8   = 8;
constexpr int I8   = 8;
constexpr int KS   = 7;
constexpr int S49  = KS * KS;        // 49
constexpr int CIN  = 128;
constexpr int COUT = 128;
constexpr int SLICE = G8 * S49;      // 392 floats per (co,ci)
constexpr int CI_PER_BLK = 4;        // ci packed into float4 LDS lanes
constexpr int NT = 448;              // threads 0..391 map to (i,s)
constexpr int RUN = CI_PER_BLK * SLICE; // 1568 floats: contiguous output per (co,o) chunk
}

__global__ __launch_bounds__(NT) void expand_kernel(
    const float* __restrict__ weight,   // [COUT, CIN, G, 7, 7]
    const float* __restrict__ in_H,     // [8]
    const float* __restrict__ out_H,    // [8]
    const float* __restrict__ grid_Rn,  // [7,7,2]
    const float* __restrict__ mask,     // [7,7]
    float* __restrict__ out)            // [COUT, O, CIN, I, 7, 7]
{
    __shared__ float4 Wl[SLICE];        // [g*49+p] -> {ci0..ci0+3}
    __shared__ float4 wtab[O8 * S49];   // per-(o,s) bilinear weights * mask
    __shared__ unsigned int ttab[O8 * S49]; // per-(o,s) packed tap indices
    __shared__ unsigned int hg[O8 * I8];
    __shared__ float hw[O8 * I8];
    __shared__ __align__(16) float stag[2][RUN]; // double-buffered store staging

    const int tid = threadIdx.x;
    const int bx  = blockIdx.x;
    const int co  = bx >> 5;                 // 32 blocks per co (128 ci / 4)
    const int ci0 = (bx & 31) * CI_PER_BLK;

    // ---- weight staging: transpose 4 ci-slices into float4-interleaved LDS ----
    if (tid < SLICE) {
        const float* b0 = weight + (size_t)(co * CIN + ci0) * SLICE + tid;
        float4 v;
        v.x = b0[0];
        v.y = b0[SLICE];
        v.z = b0[2 * SLICE];
        v.w = b0[3 * SLICE];
        Wl[tid] = v;

        // ---- geometry tables: one thread per (o,s) combo ----
        const int o = tid / S49;
        const int s = tid - o * S49;
        const float gx = grid_Rn[2 * s];
        const float gy = grid_Rn[2 * s + 1];
        const float mv = mask[s];
        const float a  = -out_H[o];          // out_inv, same as reference
        const float c  = cosf(a);
        const float sn = sinf(a);
        const float rx = c * gx - sn * gy;   // left_apply_to_Rn
        const float ry = sn * gx + c * gy;
        const float px = (rx + 1.0f) * 0.5f * (float)(KS - 1);
        const float py = (ry + 1.0f) * 0.5f * (float)(KS - 1);
        const float fx0 = floorf(px), fy0 = floorf(py);
        const float wx = px - fx0, wy = py - fy0;
        const int x0 = (int)fx0, y0 = (int)fy0;
        const int x1 = x0 + 1,   y1 = y0 + 1;
        const int xc0 = min(max(x0, 0), KS - 1);
        const int xc1 = min(max(x1, 0), KS - 1);
        const int yc0 = min(max(y0, 0), KS - 1);
        const int yc1 = min(max(y1, 0), KS - 1);
        const bool ix0 = (x0 >= 0) && (x0 <= KS - 1);
        const bool ix1 = (x1 >= 0) && (x1 <= KS - 1);
        const bool iy0 = (y0 >= 0) && (y0 <= KS - 1);
        const bool iy1 = (y1 >= 0) && (y1 <= KS - 1);
        float w00 = (1.0f - wx) * (1.0f - wy); w00 = (ix0 && iy0) ? w00 : 0.0f;
        float w10 = wx * (1.0f - wy);          w10 = (ix1 && iy0) ? w10 : 0.0f;
        float w01 = (1.0f - wx) * wy;          w01 = (ix0 && iy1) ? w01 : 0.0f;
        float w11 = wx * wy;                   w11 = (ix1 && iy1) ? w11 : 0.0f;
        float4 wv;                            // premultiplied by mask (bf16-absorbed reassoc)
        wv.x = w00 * mv; wv.y = w10 * mv; wv.z = w01 * mv; wv.w = w11 * mv;
        wtab[tid] = wv;
        const unsigned t00 = (unsigned)(yc0 * KS + xc0);
        const unsigned t10 = (unsigned)(yc0 * KS + xc1);
        const unsigned t01 = (unsigned)(yc1 * KS + xc0);
        const unsigned t11 = (unsigned)(yc1 * KS + xc1);
        ttab[tid] = t00 | (t10 << 8) | (t01 << 16) | (t11 << 24);
    }
    if (tid < O8 * I8) {                     // threads 0..63: H-interp table
        const int o = tid >> 3, i = tid & 7;
        const float TP   = 6.28318530717958647692f;   // float32(2*pi)
        const float STEP = 0.78539816339744830961f;   // float32(2*pi/8)
        float q = -out_H[o] + in_H[i];
        float m = fmodf(q, TP);
        if (m < 0.0f) m += TP;               // jnp.mod semantics
        const float pos = m / STEP;
        const float b = floorf(pos);
        const int i0 = ((int)b) & 7;         // b in [0,8], 8&7==0 matches %8
        const int i1 = (i0 + 1) & 7;
        hg[tid] = (unsigned)(i0 * S49) | ((unsigned)(i1 * S49) << 16);
        hw[tid] = pos - b;
    }
    __syncthreads();

    // active threads: tid 0..391 (wave 6 partially active; all 7 waves reach barriers)
    const bool active = (tid < SLICE);
    const int i  = active ? (tid / S49) : 0;          // 0..7
    const int s  = active ? (tid - i * S49) : 0;      // 0..48
    const int sci = tid / (SLICE / CI_PER_BLK);       // store-phase ci (tid/98), 0..3
    const int se4 = tid - sci * (SLICE / CI_PER_BLK); // store-phase float4 idx, 0..97

    // contiguous 1568-float output chunk per (co,o): [co][o][ci0..ci0+3][392]
    size_t ochunk = ((size_t)(co * O8) * CIN + ci0) * SLICE;

    #pragma unroll
    for (int o = 0; o < O8; ++o) {
        float* sb = stag[o & 1];
        if (active) {
            const float4 wv = wtab[o * S49 + s];
            const unsigned tp = ttab[o * S49 + s];
            const int t00 = (int)(tp & 0xffu);
            const int t10 = (int)((tp >> 8) & 0xffu);
            const int t01 = (int)((tp >> 16) & 0xffu);
            const int t11 = (int)(tp >> 24);

            const unsigned hp = hg[(o << 3) + i];
            const float    wh = hw[(o << 3) + i];
            const int g0 = (int)(hp & 0xffffu);
            const int g1 = (int)(hp >> 16);

            float ax, ay, az, aw;
            const bool lo = (wh <= 1e-4f);
            const bool hi = (wh >= 1.0f - 1e-4f);
            if (lo || hi) {
                // degenerate H-blend: single slice; dropped term <= 1e-4*|W| ~ 5e-7
                const int   g  = lo ? g0 : g1;
                const float sc = lo ? (1.0f - wh) : wh;
                const float4 v00 = Wl[g + t00];
                const float4 v10 = Wl[g + t10];
                const float4 v01 = Wl[g + t01];
                const float4 v11 = Wl[g + t11];
                ax = sc * (wv.x * v00.x + wv.y * v10.x + wv.z * v01.x + wv.w * v11.x);
                ay = sc * (wv.x * v00.y + wv.y * v10.y + wv.z * v01.y + wv.w * v11.y);
                az = sc * (wv.x * v00.z + wv.y * v10.z + wv.z * v01.z + wv.w * v11.z);
                aw = sc * (wv.x * v00.w + wv.y * v10.w + wv.z * v01.w + wv.w * v11.w);
            } else {
                const float4 u00 = Wl[g0 + t00];
                const float4 u10 = Wl[g0 + t10];
                const float4 u01 = Wl[g0 + t01];
                const float4 u11 = Wl[g0 + t11];
                const float4 v00 = Wl[g1 + t00];
                const float4 v10 = Wl[g1 + t10];
                const float4 v01 = Wl[g1 + t01];
                const float4 v11 = Wl[g1 + t11];
                const float wA = (1.0f - wh), wB = wh;
                ax = wA * (wv.x * u00.x + wv.y * u10.x + wv.z * u01.x + wv.w * u11.x)
                   + wB * (wv.x * v00.x + wv.y * v10.x + wv.z * v01.x + wv.w * v11.x);
                ay = wA * (wv.x * u00.y + wv.y * u10.y + wv.z * u01.y + wv.w * u11.y)
                   + wB * (wv.x * v00.y + wv.y * v10.y + wv.z * v01.y + wv.w * v11.y);
                az = wA * (wv.x * u00.z + wv.y * u10.z + wv.z * u01.z + wv.w * u11.z)
                   + wB * (wv.x * v00.z + wv.y * v10.z + wv.z * v01.z + wv.w * v11.z);
                aw = wA * (wv.x * u00.w + wv.y * u10.w + wv.z * u01.w + wv.w * u11.w)
                   + wB * (wv.x * v00.w + wv.y * v10.w + wv.z * v01.w + wv.w * v11.w);
            }
            // stage results: [ci][e] layout inside the 1568-float chunk
            sb[            tid] = ax;
            sb[    SLICE + tid] = ay;
            sb[2 * SLICE + tid] = az;
            sb[3 * SLICE + tid] = aw;
        }
        __syncthreads();   // staging visible; also orders o+2 writes after o reads
        if (active) {
            const float4 sv = *reinterpret_cast<const float4*>(&sb[sci * SLICE + 4 * se4]);
            float4* dst = reinterpret_cast<float4*>(out + ochunk + sci * SLICE + 4 * se4);
            *dst = sv;
        }
        ochunk += (size_t)CIN * SLICE;       // advance o by 128*392
    }
}

extern "C" void kernel_launch(void* const* d_in, const int* in_sizes, int n_in,
                              void* d_out, int out_size, void* d_ws, size_t ws_size,
                              hipStream_t stream) {
    const float* weight  = (const float*)d_in[0];
    const float* in_H    = (const float*)d_in[1];
    const float* out_H   = (const float*)d_in[2];
    /* d_in[3] = grid_H (unused) */
    const float* grid_Rn = (const float*)d_in[4];
    const float* mask    = (const float*)d_in[5];
    float* outp = (float*)d_out;

    const int nblocks = COUT * (CIN / CI_PER_BLK);  // 4096
    hipLaunchKernelGGL(expand_kernel, dim3(nblocks), dim3(NT), 0, stream,
                       weight, in_H, out_H, grid_Rn, mask, outp);
}